// Round 1
// baseline (543.666 us; speedup 1.0000x reference)
//
#include <hip/hip_runtime.h>

// Problem constants (from reference: shape (2,1,384,1248), MAXDISP=128, C=1)
#define NB 2
#define HH 384
#define WW 1248
#define W4 (WW / 4)        // 312 float4 per row
#define MAXDISP 128

// out[n, d, y, x] = x >= d ? |img1[n,0,y,x] - img2[n,0,y,x-d]| : 0
// Output layout: ((n*128 + d)*384 + y)*1248 + x   (C==1)
//
// Memory-bound: 490.7 MB written once; inputs (2x 3.83 MB) live in L2.
// One thread produces one float4 of output (coalesced 16B stores).
__global__ __launch_bounds__(256) void cost_volume_kernel(
    const float* __restrict__ img1,
    const float* __restrict__ img2,
    float* __restrict__ out)
{
    const int d = blockIdx.y;           // disparity 0..127
    const int n = blockIdx.z;           // batch 0..1

    // flat index over (y, x4) for this (n, d) slice
    const int idx = blockIdx.x * 256 + threadIdx.x;   // 0 .. H*W4-1 (exact: 468*256 = 119808)
    const int x4  = idx % W4;
    const int y   = idx / W4;

    const float* __restrict__ row1 = img1 + (n * HH + y) * WW;
    const float* __restrict__ row2 = img2 + (n * HH + y) * WW;

    const int x = x4 * 4;

    // aligned 16B load of left image
    const float4 a = *(const float4*)(row1 + x);

    // shifted source column; clamp keeps loads in-bounds (reference clips too),
    // mask zeroes the out-of-range elements -> predication, no divergence
    const int s0 = x - d;
    float4 o;
    {
        const int c0 = max(s0 + 0, 0);
        const int c1 = max(s0 + 1, 0);
        const int c2 = max(s0 + 2, 0);
        const int c3 = max(s0 + 3, 0);
        const float b0 = row2[c0];
        const float b1 = row2[c1];
        const float b2 = row2[c2];
        const float b3 = row2[c3];
        o.x = (s0 + 0 >= 0) ? fabsf(a.x - b0) : 0.0f;
        o.y = (s0 + 1 >= 0) ? fabsf(a.y - b1) : 0.0f;
        o.z = (s0 + 2 >= 0) ? fabsf(a.z - b2) : 0.0f;
        o.w = (s0 + 3 >= 0) ? fabsf(a.w - b3) : 0.0f;
    }

    // output float4 index: ((n*D + d)*H*W4) + idx
    const size_t o4 = ((size_t)(n * MAXDISP + d) * (HH * (size_t)W4)) + (size_t)idx;
    *(float4*)(out + o4 * 4) = o;
}

extern "C" void kernel_launch(void* const* d_in, const int* in_sizes, int n_in,
                              void* d_out, int out_size, void* d_ws, size_t ws_size,
                              hipStream_t stream) {
    const float* img1 = (const float*)d_in[0];
    const float* img2 = (const float*)d_in[1];
    float* out = (float*)d_out;

    // H*W4 = 384*312 = 119808 = 468 * 256 exactly
    dim3 grid((HH * W4) / 256, MAXDISP, NB);
    dim3 block(256);
    cost_volume_kernel<<<grid, block, 0, stream>>>(img1, img2, out);
}